// Round 3
// baseline (125.637 us; speedup 1.0000x reference)
//
#include <hip/hip_runtime.h>
#include <hip/hip_bf16.h>

// Problem constants
#define B_  2
#define S_  2048
#define E_  512
#define H_  8
#define D_  64
#define BS_ (B_ * S_)   // 4096 rows
#define N1_ 1536        // fused tri-projection output cols
#define K_  512

typedef __bf16 bf16x8 __attribute__((ext_vector_type(8)));
typedef float  f32x4  __attribute__((ext_vector_type(4)));
typedef unsigned short us8 __attribute__((ext_vector_type(8)));

// float -> bf16 (RNE) bit trick
__device__ __forceinline__ ushort f2bf(float f) {
    unsigned u = __float_as_uint(f);
    unsigned r = (u + 0x7FFFu + ((u >> 16) & 1u)) >> 16;
    return (ushort)r;
}
__device__ __forceinline__ float bf2f(ushort b) {
    return __uint_as_float(((unsigned)b) << 16);
}

// async global->LDS, 16 B per lane; LDS dest = wave-uniform base + lane*16
__device__ __forceinline__ void gld_lds16(const ushort* g, ushort* l) {
    __builtin_amdgcn_global_load_lds(
        (const __attribute__((address_space(1))) unsigned int*)g,
        (__attribute__((address_space(3))) unsigned int*)l, 16, 0, 0);
}

// ---------------- prep kernel: weight transposes only ----------------
// 256 blocks: 64x64 transpose tiles of the four 512x512 weights.
__global__ __launch_bounds__(256) void prep_kernel(
    const float* __restrict__ Wp, const float* __restrict__ Wc,
    const float* __restrict__ Ws, const float* __restrict__ Wo,
    ushort* __restrict__ Wcat_t, ushort* __restrict__ Wo_t) {
    __shared__ ushort T[64][65];
    int bid2 = blockIdx.x;                // 0..255
    int tid = threadIdx.x;
    int z = bid2 >> 6;
    int t = bid2 & 63;
    const float* src = (z == 0) ? Wp : (z == 1) ? Wc : (z == 2) ? Ws : Wo;
    ushort* dst = (z < 3) ? (Wcat_t + (size_t)z * 512 * 512) : Wo_t;
    int n0 = (t & 7) * 64, k0 = (t >> 3) * 64;
    int g = tid >> 6, l = tid & 63;
    #pragma unroll
    for (int r = 0; r < 16; r++) {
        int kk = g * 16 + r;
        T[kk][l] = f2bf(src[(size_t)(k0 + kk) * 512 + n0 + l]);  // coalesced read
    }
    __syncthreads();
    #pragma unroll
    for (int r = 0; r < 16; r++) {
        int nn = g * 16 + r;
        dst[(size_t)(n0 + nn) * 512 + k0 + l] = T[l][nn];        // coalesced write
    }
}

// ---------------- bf16 MFMA GEMM1 (2-phase, XCD-swizzled, fp32-A) ----------------
// Unchanged from round-2 (measured neutral vs round-0/1; kept for attribution).
template<int TM, int TN, bool BF16OUT, bool A32>
__global__ __launch_bounds__(256) void gemm_mfma_kernel(
    const void* __restrict__ Av,    // M x K (fp32 if A32 else bf16)
    const ushort* __restrict__ Bt,  // N x K
    const float*  __restrict__ b0,  // bias cols [0,512)
    const float*  __restrict__ b1,  // bias cols [512,1024)
    const float*  __restrict__ b2,  // bias cols [1024,1536)
    void* __restrict__ Cv,          // M x N
    int N, int K) {
    constexpr int TK = 64;
    constexpr int FM = TM / 32;          // m-frags per wave
    constexpr int NF = TN / 32;          // n-frags per wave
    __shared__ ushort As[2][TM][TK];     // no pad (global_load_lds layout)
    __shared__ ushort Bs[2][TN][TK];

    const ushort* Ab = (const ushort*)Av;
    const float*  Af = (const float*)Av;

    const int tid  = threadIdx.x;
    const int lane = tid & 63;
    const int wave = tid >> 6;
    const int wm = wave >> 1, wn = wave & 1;

    // bijective XCD swizzle (nwg=512; nwg%8==0)
    const int nbx = gridDim.x;
    const int nwg = gridDim.x * gridDim.y;
    const int lin = blockIdx.y * nbx + blockIdx.x;
    const int swz = (lin & 7) * (nwg >> 3) + (lin >> 3);
    const int row0 = (swz / nbx) * TM;
    const int col0 = (swz % nbx) * TN;

    f32x4 acc[FM][NF] = {};

    const int srow = lane >> 3;          // 0..7 row within an 8-row issue
    const int scol = (lane & 7) * 8;     // 8-element chunk

    const int lrow = lane & 15;
    const int lk   = (lane >> 4) * 8;

    const int arow = wave * (TM / 4) + srow;   // this lane's A-stage row
    const ushort* gab = Ab + (size_t)(row0 + arow) * K + scol;
    const float*  gaf = Af + (size_t)(row0 + arow) * K + scol;
    const ushort* gbb = Bt + (size_t)(col0 + wave * (TN / 4) + srow) * K + scol;

    auto stageB = [&](int buf, int kt) {
        const ushort* gb = gbb + kt;
        #pragma unroll
        for (int j = 0; j < NF; j++)
            gld_lds16(gb + (size_t)j * 8 * K, &Bs[buf][wave * (TN / 4) + j * 8][0]);
    };
    auto stageA_lds = [&](int buf, int kt) {
        const ushort* ga = gab + kt;
        #pragma unroll
        for (int j = 0; j < FM; j++)
            gld_lds16(ga + (size_t)j * 8 * K, &As[buf][wave * (TM / 4) + j * 8][0]);
    };

    f32x4 ar[FM][2];                     // fp32 A staging regs (A32 path)
    auto loadA_regs = [&](int kt) {
        #pragma unroll
        for (int j = 0; j < FM; j++) {
            const float* p = gaf + (size_t)j * 8 * K + kt;
            ar[j][0] = *(const f32x4*)p;
            ar[j][1] = *(const f32x4*)(p + 4);
        }
    };
    auto writeA_lds = [&](int buf) {
        #pragma unroll
        for (int j = 0; j < FM; j++) {
            us8 o;
            #pragma unroll
            for (int q = 0; q < 4; q++) { o[q] = f2bf(ar[j][0][q]); o[q + 4] = f2bf(ar[j][1][q]); }
            *(us8*)(&As[buf][arow + j * 8][scol]) = o;
        }
    };

    // prologue: tile 0 into buf 0
    if (A32) {
        loadA_regs(0);
        stageB(0, 0);
        writeA_lds(0);
    } else {
        stageA_lds(0, 0);
        stageB(0, 0);
    }
    __syncthreads();

    const int nt = K / TK;
    int cur = 0;
    for (int t = 0; t < nt; t++) {
        if (t + 1 < nt) {                // next-tile loads in flight under MFMA
            if (A32) loadA_regs((t + 1) * TK);
            else     stageA_lds(cur ^ 1, (t + 1) * TK);
            stageB(cur ^ 1, (t + 1) * TK);
        }
        #pragma unroll
        for (int kk = 0; kk < TK; kk += 32) {
            bf16x8 af[FM], bfr[NF];
            #pragma unroll
            for (int i = 0; i < FM; i++)
                af[i] = *(const bf16x8*)(&As[cur][wm * (FM * 16) + i * 16 + lrow][kk + lk]);
            #pragma unroll
            for (int j = 0; j < NF; j++)
                bfr[j] = *(const bf16x8*)(&Bs[cur][wn * (TN / 2) + j * 16 + lrow][kk + lk]);
            #pragma unroll
            for (int i = 0; i < FM; i++)
                #pragma unroll
                for (int j = 0; j < NF; j++)
                    acc[i][j] = __builtin_amdgcn_mfma_f32_16x16x32_bf16(
                        af[i], bfr[j], acc[i][j], 0, 0, 0);
        }
        if (A32 && (t + 1 < nt)) writeA_lds(cur ^ 1);  // cvt+ds_write before publish
        __syncthreads();                 // drains vmcnt+lgkm: next tile ready
        cur ^= 1;
    }

    // C/D layout: col = lane&15, row = (lane>>4)*4 + reg  [m89/m91 verified]
    const int ccol = lane & 15;
    const int crow = (lane >> 4) * 4;
    #pragma unroll
    for (int j = 0; j < NF; j++) {
        int gcol = col0 + wn * (TN / 2) + j * 16 + ccol;
        float bias = (gcol < 512) ? b0[gcol]
                   : (gcol < 1024) ? b1[gcol - 512] : b2[gcol - 1024];
        #pragma unroll
        for (int i = 0; i < FM; i++) {
            int grow = row0 + wm * (FM * 16) + i * 16 + crow;
            #pragma unroll
            for (int rg = 0; rg < 4; rg++) {
                float v = acc[i][j][rg] + bias;
                if (BF16OUT)
                    ((ushort*)Cv)[(size_t)(grow + rg) * N + gcol] = f2bf(v);
                else
                    ((float*)Cv)[(size_t)(grow + rg) * N + gcol] = v;
            }
        }
    }
}

// ---------------- FUSED tree attention + GEMM2 ----------------
// Round-15: one block per 16 output rows (grid 256 = 1 block/CU, 148 KB LDS).
// Phase A: each wave computes attn for 4 of the block's 16 tokens (round-2
//   ballot-scan logic verbatim) and writes the 512-wide bf16 row into LDS As
//   (XOR-swizzled cols -> conflict-free A-frag reads). B tile-0 staging is
//   issued BEFORE phase A so its 64 KB hides under the scan.
// Phase B: out[16x512] = As(16x512) @ Wo_t^T + bo via MFMA, full-width N split
//   across the 4 waves (NF=8), 2-phase double-buffered Bs (T3-minimum).
// Removes: one dispatch gap + the 8 MB attn_bf global round-trip.
__global__ __launch_bounds__(256) void attn_gemm2_kernel(
    const ushort* __restrict__ PCS, const int* __restrict__ parent,
    const ushort* __restrict__ Wo_t, const float* __restrict__ bo,
    float* __restrict__ out) {
    constexpr int CAP = 16;
    __shared__ ushort As[16][512];        // 16 KB attn rows (swizzled)
    __shared__ ushort Bs[2][512][64];     // 128 KB Wo_t staging
    __shared__ int clist[4][4][CAP];      // 1 KB child lists

    const int tid  = threadIdx.x;
    const int lane = tid & 63;
    const int wv   = tid >> 6;
    const int r0   = blockIdx.x * 16;
    const int bbase = (r0 >> 11) << 11;

    const int srow = lane >> 3;
    const int scol = (lane & 7) * 8;
    auto stageB = [&](int buf, int kt) {
        #pragma unroll
        for (int j = 0; j < 16; j++) {
            const ushort* g = Wo_t + (size_t)(wv * 128 + j * 8 + srow) * K_ + kt + scol;
            gld_lds16(g, &Bs[buf][wv * 128 + j * 8][0]);
        }
    };
    stageB(0, 0);                         // hides under the attn phase

    // ---- phase A: attention for this wave's 4 tokens ----
    for (int tt = 0; tt < 4; tt++) {
        int rloc = wv * 4 + tt;           // 0..15
        int w = r0 + rloc;
        int i = w & (S_ - 1);
        int rp = bbase + parent[w];

        us8 p8 = *(const us8*)(PCS + (size_t)w * N1_ + lane * 8);
        const ushort* rm = PCS + (size_t)rp * N1_;
        us8 pc8 = *(const us8*)(rm + 512  + lane * 8);
        us8 ps8 = *(const us8*)(rm + 1024 + lane * 8);

        float pnf[8];
        #pragma unroll
        for (int j = 0; j < 8; j++) pnf[j] = bf2f(p8[j]);

        float Z = 0.f, av[8] = {0.f, 0.f, 0.f, 0.f, 0.f, 0.f, 0.f, 0.f};

        int cnt = 0;
        for (int t0 = 0; t0 < S_; t0 += 256) {
            int4 pv = *(const int4*)(parent + bbase + t0 + lane * 4);
            int pc[4] = {pv.x, pv.y, pv.z, pv.w};
            #pragma unroll
            for (int jj = 0; jj < 4; jj++) {
                int c = bbase + t0 + lane * 4 + jj;
                bool mine = (pc[jj] == i) && (c != rp);   // mutual/self once
                unsigned long long m2 = __ballot(mine);
                if (m2) {                                  // wave-uniform
                    int nb = __popcll(m2);
                    if (cnt + nb <= CAP) {
                        if (mine) {
                            int slot = cnt + __popcll(m2 & ((1ull << lane) - 1ull));
                            clist[wv][tt][slot] = c;
                        }
                        cnt += nb;
                    } else {
                        // overflow fallback: inline serial processing (rare)
                        unsigned long long mm = m2;
                        while (mm) {
                            int l = __ffsll(mm) - 1;
                            mm &= mm - 1;
                            int cc = bbase + t0 + l * 4 + jj;
                            const ushort* rc = PCS + (size_t)cc * N1_;
                            us8 c8 = *(const us8*)(rc + 512  + lane * 8);
                            us8 s8 = *(const us8*)(rc + 1024 + lane * 8);
                            float ttv = 0.f;
                            #pragma unroll
                            for (int j = 0; j < 8; j++) ttv += pnf[j] * bf2f(c8[j]);
                            ttv += __shfl_xor(ttv, 1); ttv += __shfl_xor(ttv, 2); ttv += __shfl_xor(ttv, 4);
                            float e = __expf(ttv * 0.125f);
                            Z += e;
                            #pragma unroll
                            for (int j = 0; j < 8; j++) av[j] += e * bf2f(s8[j]);
                        }
                    }
                }
            }
        }

        // parent edge (loads long since landed)
        {
            float t = 0.f;
            #pragma unroll
            for (int j = 0; j < 8; j++) t += pnf[j] * bf2f(pc8[j]);
            t += __shfl_xor(t, 1); t += __shfl_xor(t, 2); t += __shfl_xor(t, 4);
            float e = __expf(t * 0.125f);          // 1/sqrt(D) = 1/8
            Z += e;
            #pragma unroll
            for (int j = 0; j < 8; j++) av[j] += e * bf2f(ps8[j]);
        }

        // children from the collected list
        for (int e = 0; e < cnt; e++) {
            int c = clist[wv][tt][e];
            const ushort* rc = PCS + (size_t)c * N1_;
            us8 c8 = *(const us8*)(rc + 512  + lane * 8);
            us8 s8 = *(const us8*)(rc + 1024 + lane * 8);
            float t = 0.f;
            #pragma unroll
            for (int j = 0; j < 8; j++) t += pnf[j] * bf2f(c8[j]);
            t += __shfl_xor(t, 1); t += __shfl_xor(t, 2); t += __shfl_xor(t, 4);
            float e2 = __expf(t * 0.125f);
            Z += e2;
            #pragma unroll
            for (int j = 0; j < 8; j++) av[j] += e2 * bf2f(s8[j]);
        }

        float rz = 1.0f / Z;
        us8 o8;
        #pragma unroll
        for (int j = 0; j < 8; j++) o8[j] = f2bf(av[j] * rz);
        // XOR-swizzled write (16B granule): col flips bits 3..5 by row&7
        int colw = (lane * 8) ^ ((rloc & 7) << 3);
        *(us8*)(&As[rloc][colw]) = o8;
    }
    __syncthreads();   // As complete; Bs tile-0 landed (barrier drains vmcnt)

    // ---- phase B: out[16x512] = As @ Wo_t^T + bo ----
    f32x4 acc[8] = {};
    const int lrow = lane & 15;
    const int lk   = (lane >> 4) * 8;
    int cur = 0;
    for (int t = 0; t < 8; t++) {
        if (t + 1 < 8) stageB(cur ^ 1, (t + 1) * 64);   // loads fly under MFMA
        #pragma unroll
        for (int kk = 0; kk < 64; kk += 32) {
            int acol = (t * 64 + kk + lk) ^ ((lrow & 7) << 3);   // match write swz
            bf16x8 af = *(const bf16x8*)(&As[lrow][acol]);
            #pragma unroll
            for (int j = 0; j < 8; j++) {
                bf16x8 bfr = *(const bf16x8*)(&Bs[cur][wv * 128 + j * 16 + lrow][kk + lk]);
                acc[j] = __builtin_amdgcn_mfma_f32_16x16x32_bf16(af, bfr, acc[j], 0, 0, 0);
            }
        }
        __syncthreads();                 // next tile ready; cur freed for staging
        cur ^= 1;
    }

    // epilogue: C/D layout col=lane&15, row=(lane>>4)*4+reg
    const int ccol = lane & 15;
    const int crow = (lane >> 4) * 4;
    #pragma unroll
    for (int j = 0; j < 8; j++) {
        int gcol = wv * 128 + j * 16 + ccol;
        float bias = bo[gcol];
        #pragma unroll
        for (int rg = 0; rg < 4; rg++)
            out[(size_t)(r0 + crow + rg) * E_ + gcol] = acc[j][rg] + bias;
    }
}

// ---------------- launch ----------------
extern "C" void kernel_launch(void* const* d_in, const int* in_sizes, int n_in,
                              void* d_out, int out_size, void* d_ws, size_t ws_size,
                              hipStream_t stream) {
    const float* x      = (const float*)d_in[0];
    const int*   parent = (const int*)  d_in[1];
    const float* Wp     = (const float*)d_in[2];
    const float* bp     = (const float*)d_in[3];
    const float* Wc     = (const float*)d_in[4];
    const float* bc     = (const float*)d_in[5];
    const float* Ws     = (const float*)d_in[6];
    const float* bs     = (const float*)d_in[7];
    const float* Wo     = (const float*)d_in[8];
    const float* bo     = (const float*)d_in[9];
    float* out = (float*)d_out;

    char* ws = (char*)d_ws;
    // workspace layout (bytes, 256-aligned); every byte read is written first
    ushort* Wcat_t  = (ushort*)(ws + 0);          //  1,572,864
    ushort* Wo_t    = (ushort*)(ws + 1572864);    //    524,288
    ushort* PCS_bf  = (ushort*)(ws + 2097152);    // 12,582,912  (end ~14.7 MB)

    // prep: transpose weights (256 blocks)
    prep_kernel<<<256, 256, 0, stream>>>(Wp, Wc, Ws, Wo, Wcat_t, Wo_t);

    // GEMM1: PCS(bf16) = x(fp32, converted in-staging) @ [Wp|Wc|Ws] + [bp|bc|bs]
    gemm_mfma_kernel<128, 96, true, true>
        <<<dim3(N1_ / 96, BS_ / 128), 256, 0, stream>>>(
        x, Wcat_t, bp, bc, bs, PCS_bf, N1_, K_);

    // FUSED attn + GEMM2: 256 blocks x 16 rows each, out fp32 direct
    attn_gemm2_kernel<<<256, 256, 0, stream>>>(PCS_bf, parent, Wo_t, bo, out);
}

// Round 4
// 113.431 us; speedup vs baseline: 1.1076x; 1.1076x over previous
//
#include <hip/hip_runtime.h>
#include <hip/hip_bf16.h>

// Problem constants
#define B_  2
#define S_  2048
#define E_  512
#define H_  8
#define D_  64
#define BS_ (B_ * S_)   // 4096 rows
#define N1_ 1536        // fused tri-projection output cols
#define K_  512

typedef __bf16 bf16x8 __attribute__((ext_vector_type(8)));
typedef float  f32x4  __attribute__((ext_vector_type(4)));
typedef unsigned short us8 __attribute__((ext_vector_type(8)));

// float -> bf16 (RNE) bit trick
__device__ __forceinline__ ushort f2bf(float f) {
    unsigned u = __float_as_uint(f);
    unsigned r = (u + 0x7FFFu + ((u >> 16) & 1u)) >> 16;
    return (ushort)r;
}
__device__ __forceinline__ float bf2f(ushort b) {
    return __uint_as_float(((unsigned)b) << 16);
}

// async global->LDS, 16 B per lane; LDS dest = wave-uniform base + lane*16
__device__ __forceinline__ void gld_lds16(const ushort* g, ushort* l) {
    __builtin_amdgcn_global_load_lds(
        (const __attribute__((address_space(1))) unsigned int*)g,
        (__attribute__((address_space(3))) unsigned int*)l, 16, 0, 0);
}

// ---------------- merged prep kernel ----------------
// blocks [0,2048): fp32->bf16 convert of x (one float4 per thread)
// blocks [2048,2304): 64x64 transpose tiles of the four 512x512 weights
__global__ __launch_bounds__(256) void prep_kernel(
    const float* __restrict__ x, ushort* __restrict__ xb,
    const float* __restrict__ Wp, const float* __restrict__ Wc,
    const float* __restrict__ Ws, const float* __restrict__ Wo,
    ushort* __restrict__ Wcat_t, ushort* __restrict__ Wo_t) {
    int bid = blockIdx.x;
    int tid = threadIdx.x;
    if (bid < 2048) {
        int i = bid * 256 + tid;          // 524288 float4s total
        float4 v = ((const float4*)x)[i];
        ushort4 o;
        o.x = f2bf(v.x); o.y = f2bf(v.y); o.z = f2bf(v.z); o.w = f2bf(v.w);
        ((ushort4*)xb)[i] = o;
        return;
    }
    __shared__ ushort T[64][65];
    int bid2 = bid - 2048;                // 0..255
    int z = bid2 >> 6;
    int t = bid2 & 63;
    const float* src = (z == 0) ? Wp : (z == 1) ? Wc : (z == 2) ? Ws : Wo;
    ushort* dst = (z < 3) ? (Wcat_t + (size_t)z * 512 * 512) : Wo_t;
    int n0 = (t & 7) * 64, k0 = (t >> 3) * 64;
    int g = tid >> 6, l = tid & 63;
    #pragma unroll
    for (int r = 0; r < 16; r++) {
        int kk = g * 16 + r;
        T[kk][l] = f2bf(src[(size_t)(k0 + kk) * 512 + n0 + l]);  // coalesced read
    }
    __syncthreads();
    #pragma unroll
    for (int r = 0; r < 16; r++) {
        int nn = g * 16 + r;
        dst[(size_t)(n0 + nn) * 512 + k0 + l] = T[l][nn];        // coalesced write
    }
}

// ---------------- bf16 MFMA GEMM (m97 structure, tile-templated) ----------------
// C[M x N] = A[M x K](bf16) * Bt[N x K](bf16)^T + bias; output fp32 or bf16.
// 256 threads = 4 waves in 2x2; per-wave FM x NF fragments of 16x16x32.
// BK=64 (BK=128 measured -1.9us, round-12; coop grid.sync ~60us, round-11).
template<int TM, int TN, bool BF16OUT>
__global__ __launch_bounds__(256) void gemm_mfma_kernel(
    const ushort* __restrict__ A,   // M x K
    const ushort* __restrict__ Bt,  // N x K
    const float*  __restrict__ b0,  // bias cols [0,512)
    const float*  __restrict__ b1,  // bias cols [512,1024)
    const float*  __restrict__ b2,  // bias cols [1024,1536)
    void* __restrict__ Cv,          // M x N
    int N, int K) {
    constexpr int TK = 64;
    constexpr int FM = TM / 32;          // m-frags per wave
    constexpr int NF = TN / 32;          // n-frags per wave
    __shared__ ushort As[TM][TK];        // no pad (global_load_lds layout)
    __shared__ ushort Bs[TN][TK];

    const int tid  = threadIdx.x;
    const int lane = tid & 63;
    const int wave = tid >> 6;
    const int wm = wave >> 1, wn = wave & 1;
    const int row0 = blockIdx.y * TM;
    const int col0 = blockIdx.x * TN;

    f32x4 acc[FM][NF] = {};

    const int srow = lane >> 3;          // 0..7 row within an 8-row issue
    const int scol = (lane & 7) * 8;     // 8-bf16 chunk

    const int lrow = lane & 15;
    const int lk   = (lane >> 4) * 8;

    for (int kt = 0; kt < K; kt += TK) {
        const ushort* ga = A + (size_t)(row0 + wave * (TM / 4) + srow) * K + kt + scol;
        #pragma unroll
        for (int j = 0; j < FM; j++)
            gld_lds16(ga + (size_t)j * 8 * K, &As[wave * (TM / 4) + j * 8][0]);
        const ushort* gb = Bt + (size_t)(col0 + wave * (TN / 4) + srow) * K + kt + scol;
        #pragma unroll
        for (int j = 0; j < NF; j++)
            gld_lds16(gb + (size_t)j * 8 * K, &Bs[wave * (TN / 4) + j * 8][0]);
        __syncthreads();

        #pragma unroll
        for (int kk = 0; kk < TK; kk += 32) {
            bf16x8 af[FM], bfr[NF];
            #pragma unroll
            for (int i = 0; i < FM; i++)
                af[i] = *(const bf16x8*)(&As[wm * (FM * 16) + i * 16 + lrow][kk + lk]);
            #pragma unroll
            for (int j = 0; j < NF; j++)
                bfr[j] = *(const bf16x8*)(&Bs[wn * (TN / 2) + j * 16 + lrow][kk + lk]);
            #pragma unroll
            for (int i = 0; i < FM; i++)
                #pragma unroll
                for (int j = 0; j < NF; j++)
                    acc[i][j] = __builtin_amdgcn_mfma_f32_16x16x32_bf16(
                        af[i], bfr[j], acc[i][j], 0, 0, 0);
        }
        __syncthreads();
    }

    // C/D layout: col = lane&15, row = (lane>>4)*4 + reg  [m89/m91 verified]
    const int ccol = lane & 15;
    const int crow = (lane >> 4) * 4;
    #pragma unroll
    for (int j = 0; j < NF; j++) {
        int gcol = col0 + wn * (TN / 2) + j * 16 + ccol;
        float bias = (gcol < 512) ? b0[gcol]
                   : (gcol < 1024) ? b1[gcol - 512] : b2[gcol - 1024];
        #pragma unroll
        for (int i = 0; i < FM; i++) {
            int grow = row0 + wm * (FM * 16) + i * 16 + crow;
            #pragma unroll
            for (int rg = 0; rg < 4; rg++) {
                float v = acc[i][j][rg] + bias;
                if (BF16OUT)
                    ((ushort*)Cv)[(size_t)(grow + rg) * N + gcol] = f2bf(v);
                else
                    ((float*)Cv)[(size_t)(grow + rg) * N + gcol] = v;
            }
        }
    }
}

// ---------------- tree attention: 16B/lane ballot-scan gather ----------------
// PCS (bf16) row layout per token w (1536): [p(512)|c(512)|s(512)], each h*64+d.
// One wave per row n. Lane L owns 8 consecutive elements at offset L*8 of each
// 512-segment: head h = L>>3. Per edge: two dwordx4 loads, 8-FMA dot partial,
// shfl_xor(1,2,4) reduce within the 8-lane head group, one exp, 8 FMAs.
// Neighbor set {parent[n]} ∪ {m:parent[m]==n} minus duplicates, processed in
// fixed order -> bit-deterministic. No atomics.
// NOTE: alpha is PER-HEAD — the s@Wo pre-fold is invalid (round-7 post-mortem).
__global__ __launch_bounds__(256) void attn_gather_kernel(
    const ushort* __restrict__ PCS, const int* __restrict__ parent,
    ushort* __restrict__ attn) {
    int gtid = blockIdx.x * blockDim.x + threadIdx.x;
    int w    = gtid >> 6;        // token row 0..BS_-1
    int lane = gtid & 63;
    int bbase = ((w >> 11) << 11);
    int i  = w & (S_ - 1);
    int rp = bbase + parent[w];

    // p fragment: 8 consecutive bf16 at w*1536 + lane*8
    float pnf[8];
    {
        us8 p8 = *(const us8*)(PCS + (size_t)w * N1_ + lane * 8);
        #pragma unroll
        for (int j = 0; j < 8; j++) pnf[j] = bf2f(p8[j]);
    }

    float Z, av[8];
    // parent edge (always present in the mask)
    {
        const ushort* rm = PCS + (size_t)rp * N1_;
        us8 c8 = *(const us8*)(rm + 512  + lane * 8);
        us8 s8 = *(const us8*)(rm + 1024 + lane * 8);
        float t = 0.f;
        #pragma unroll
        for (int j = 0; j < 8; j++) t += pnf[j] * bf2f(c8[j]);
        t += __shfl_xor(t, 1); t += __shfl_xor(t, 2); t += __shfl_xor(t, 4);
        float e = __expf(t * 0.125f);          // 1/sqrt(D) = 1/8
        Z = e;
        #pragma unroll
        for (int j = 0; j < 8; j++) av[j] = e * bf2f(s8[j]);
    }

    // children: scan this batch's parent slice, 256 ints per step (int4/lane)
    for (int t0 = 0; t0 < S_; t0 += 256) {
        int4 pv = *(const int4*)(parent + bbase + t0 + lane * 4);
        int pc[4] = {pv.x, pv.y, pv.z, pv.w};
        #pragma unroll
        for (int jj = 0; jj < 4; jj++) {
            unsigned long long mask = __ballot(pc[jj] == i);
            while (mask) {
                int l = __ffsll(mask) - 1;
                mask &= mask - 1;
                int c = bbase + t0 + l * 4 + jj;
                if (c == rp) continue;         // mutual/self edge counted once
                const ushort* rc = PCS + (size_t)c * N1_;
                us8 c8 = *(const us8*)(rc + 512  + lane * 8);
                us8 s8 = *(const us8*)(rc + 1024 + lane * 8);
                float t = 0.f;
                #pragma unroll
                for (int j = 0; j < 8; j++) t += pnf[j] * bf2f(c8[j]);
                t += __shfl_xor(t, 1); t += __shfl_xor(t, 2); t += __shfl_xor(t, 4);
                float e = __expf(t * 0.125f);
                Z += e;
                #pragma unroll
                for (int j = 0; j < 8; j++) av[j] += e * bf2f(s8[j]);
            }
        }
    }

    float rz = 1.0f / Z;
    us8 o8;
    #pragma unroll
    for (int j = 0; j < 8; j++) o8[j] = f2bf(av[j] * rz);
    *(us8*)(attn + (size_t)w * E_ + lane * 8) = o8;
}

// ---------------- launch ----------------
extern "C" void kernel_launch(void* const* d_in, const int* in_sizes, int n_in,
                              void* d_out, int out_size, void* d_ws, size_t ws_size,
                              hipStream_t stream) {
    const float* x      = (const float*)d_in[0];
    const int*   parent = (const int*)  d_in[1];
    const float* Wp     = (const float*)d_in[2];
    const float* bp     = (const float*)d_in[3];
    const float* Wc     = (const float*)d_in[4];
    const float* bc     = (const float*)d_in[5];
    const float* Ws     = (const float*)d_in[6];
    const float* bs     = (const float*)d_in[7];
    const float* Wo     = (const float*)d_in[8];
    const float* bo     = (const float*)d_in[9];
    float* out = (float*)d_out;

    char* ws = (char*)d_ws;
    // workspace layout (bytes, 256-aligned); every byte read is written first
    ushort* x_bf    = (ushort*)(ws + 0);          //  4,194,304
    ushort* Wcat_t  = (ushort*)(ws + 4194304);    //  1,572,864
    ushort* Wo_t    = (ushort*)(ws + 5767168);    //    524,288
    ushort* PCS_bf  = (ushort*)(ws + 6291456);    // 12,582,912
    ushort* attn_bf = (ushort*)(ws + 18874368);   //  4,194,304  (end ~23.1 MB)

    // prep: convert x (2048 blocks) + transpose weights (256 blocks)
    prep_kernel<<<2304, 256, 0, stream>>>(x, x_bf, Wp, Wc, Ws, Wo, Wcat_t, Wo_t);

    // GEMM1: PCS(bf16) = x @ [Wp|Wc|Ws] + [bp|bc|bs]
    // 128x96 tile -> 16x32 = 512 blocks = exactly 2.0 blocks/CU
    gemm_mfma_kernel<128, 96, true>
        <<<dim3(N1_ / 96, BS_ / 128), 256, 0, stream>>>(
        x_bf, Wcat_t, bp, bc, bs, PCS_bf, N1_, K_);

    // tree attention: deterministic gather, 16B/lane loads, no atomics
    attn_gather_kernel<<<BS_ * 64 / 256, 256, 0, stream>>>(
        PCS_bf, parent, attn_bf);

    // GEMM2: out(fp32) = attn @ Wo + bo
    // 64x64 tile -> 8x64 = 512 blocks = 2.0 blocks/CU
    gemm_mfma_kernel<64, 64, false>
        <<<dim3(E_ / 64, BS_ / 64), 256, 0, stream>>>(
        attn_bf, Wo_t, bo, bo, bo, out, E_, K_);
}